// Round 1
// baseline (2865.691 us; speedup 1.0000x reference)
//
#include <hip/hip_runtime.h>
#include <math.h>

#define ND  256    // num_data (steps)
#define SEQ 2048
#define NI  256
#define NH  1024
#define NO  256

#define MAIN_BLOCKS  128
#define MAIN_THREADS 512          // 8 waves
#define H_PER_BLOCK  (NH / MAIN_BLOCKS)   // 8

// ---------------- device-scope grid barrier (sense = generation counter) ----
__device__ __forceinline__ void gbar(int* bar, int nblk) {
    __syncthreads();
    if (threadIdx.x == 0) {
        int* cnt = bar;        // bar[0]
        int* gen = bar + 32;   // separate cache line
        __threadfence();
        int g = __hip_atomic_load(gen, __ATOMIC_RELAXED, __HIP_MEMORY_SCOPE_AGENT);
        int a = __hip_atomic_fetch_add(cnt, 1, __ATOMIC_ACQ_REL, __HIP_MEMORY_SCOPE_AGENT);
        if (a == nblk - 1) {
            __hip_atomic_store(cnt, 0, __ATOMIC_RELAXED, __HIP_MEMORY_SCOPE_AGENT);
            __hip_atomic_store(gen, g + 1, __ATOMIC_RELEASE, __HIP_MEMORY_SCOPE_AGENT);
        } else {
            while (__hip_atomic_load(gen, __ATOMIC_RELAXED, __HIP_MEMORY_SCOPE_AGENT) == g) {
                __builtin_amdgcn_s_sleep(2);
            }
        }
        __threadfence();
    }
    __syncthreads();
}

// ---------------- input projections: X[t][h] = b[h] + x[t,2047,:] @ W_in ----
__global__ void xproj(const float* __restrict__ x,
                      const float* __restrict__ Win1, const float* __restrict__ b1,
                      const float* __restrict__ Win2, const float* __restrict__ b2,
                      float* __restrict__ X1, float* __restrict__ X2) {
    int t     = blockIdx.y;
    int layer = blockIdx.z;
    int h     = blockIdx.x * 256 + threadIdx.x;
    const float* W = layer ? Win2 : Win1;
    const float* b = layer ? b2   : b1;
    float*       X = layer ? X2   : X1;
    __shared__ float lx[NI];
    lx[threadIdx.x] = x[(size_t)t * SEQ * NI + (size_t)(SEQ - 1) * NI + threadIdx.x];
    __syncthreads();
    float acc = b[h];
    #pragma unroll 8
    for (int i = 0; i < NI; ++i)
        acc += lx[i] * W[i * NH + h];          // coalesced over h
    X[t * NH + h] = acc;
}

// ---------------- sequential recurrence, weights LDS-resident ----------------
__launch_bounds__(MAIN_THREADS, 1)
__global__ void recur(const float* __restrict__ Wr1, const float* __restrict__ Wr2,
                      const float* __restrict__ X1,  const float* __restrict__ X2,
                      float* Z12, float* Z2, float* Z1hist, int* bar) {
    __shared__ float lW1[H_PER_BLOCK][NH];   // 32 KB
    __shared__ float lW2[H_PER_BLOCK][NH];   // 32 KB
    const int tid = threadIdx.x;
    const int b   = blockIdx.x;
    const int h0  = b * H_PER_BLOCK;

    // one-time load of this block's weight columns (Wr[k][h0+hw]) into LDS
    for (int idx = tid; idx < H_PER_BLOCK * NH; idx += MAIN_THREADS) {
        int hw = idx >> 10;            // 0..7
        int k  = idx & (NH - 1);       // 0..1023
        lW1[hw][k] = Wr1[(size_t)k * NH + h0 + hw];
        lW2[hw][k] = Wr2[(size_t)k * NH + h0 + hw];
    }
    __syncthreads();

    const int w = tid >> 6;            // wave 0..7
    const int l = tid & 63;            // lane
    const int h = h0 + w;              // this wave's hidden unit
    int cur = 0;

    for (int t = 0; t < ND; ++t) {
        const float* z12 = Z12 + cur * NH;
        const float* z2  = Z2  + cur * NH;
        const bool even  = (t & 1) == 0;

        float xv1 = X1[t * NH + h];                  // wave-uniform scalar load
        float xv2 = even ? X2[t * NH + h] : 0.0f;

        float r1 = 0.0f, r2 = 0.0f;
        #pragma unroll
        for (int j = 0; j < 16; ++j) {
            int k = l + 64 * j;                      // coalesced global, bank-free LDS
            r1 += z12[k] * lW1[w][k];
        }
        if (even) {
            #pragma unroll
            for (int j = 0; j < 16; ++j) {
                int k = l + 64 * j;
                r2 += z2[k] * lW2[w][k];
            }
        }
        #pragma unroll
        for (int off = 32; off; off >>= 1) {
            r1 += __shfl_xor(r1, off, 64);
            r2 += __shfl_xor(r2, off, 64);
        }

        if (l == 0) {
            float z1n = tanhf(xv1 + r1);
            float z2n = even ? tanhf(xv2 + r2) : z2[h];
            Z1hist[t * NH + h]        = z1n;
            Z12[(cur ^ 1) * NH + h]   = z1n + z2n;
            Z2 [(cur ^ 1) * NH + h]   = z2n;
        }
        gbar(bar, MAIN_BLOCKS);
        cur ^= 1;
    }
}

// ---------------- output projection: out[t] = tanh(Z1hist[t] @ W_out + b) ----
__global__ void outproj(const float* __restrict__ Z1hist,
                        const float* __restrict__ Wout,
                        const float* __restrict__ bout,
                        float* __restrict__ out) {
    int t = blockIdx.x;
    int o = threadIdx.x;
    __shared__ float lz[NH];
    for (int i = threadIdx.x; i < NH; i += 256)
        lz[i] = Z1hist[t * NH + i];
    __syncthreads();
    float acc = bout[o];
    #pragma unroll 8
    for (int hh = 0; hh < NH; ++hh)
        acc += lz[hh] * Wout[hh * NO + o];           // coalesced over o
    out[t * NO + o] = tanhf(acc);
}

extern "C" void kernel_launch(void* const* d_in, const int* in_sizes, int n_in,
                              void* d_out, int out_size, void* d_ws, size_t ws_size,
                              hipStream_t stream) {
    const float* x     = (const float*)d_in[0];
    const float* Win1  = (const float*)d_in[1];
    const float* b1    = (const float*)d_in[2];
    const float* Wr1   = (const float*)d_in[3];
    const float* Win2  = (const float*)d_in[4];
    const float* b2    = (const float*)d_in[5];
    const float* Wr2   = (const float*)d_in[6];
    const float* Wout  = (const float*)d_in[7];
    const float* bout  = (const float*)d_in[8];
    float* out = (float*)d_out;

    // workspace layout (floats)
    float* ws   = (float*)d_ws;
    float* Z12  = ws;                       // 2*NH
    float* Z2   = Z12 + 2 * NH;             // 2*NH
    int*   bar  = (int*)(Z2 + 2 * NH);      // 64 ints
    float* Z1h  = (float*)(bar + 64);       // ND*NH
    float* X1   = Z1h + ND * NH;            // ND*NH
    float* X2   = X1 + ND * NH;             // ND*NH

    // zero initial state + barrier (ws is poisoned 0xAA before every call)
    hipMemsetAsync(Z12, 0, (4 * NH) * sizeof(float) + 64 * sizeof(int), stream);

    dim3 xg(NH / 256, ND, 2);
    xproj<<<xg, 256, 0, stream>>>(x, Win1, b1, Win2, b2, X1, X2);

    recur<<<MAIN_BLOCKS, MAIN_THREADS, 0, stream>>>(Wr1, Wr2, X1, X2, Z12, Z2, Z1h, bar);

    outproj<<<ND, NO, 0, stream>>>(Z1h, Wout, bout, out);
}

// Round 2
// 1695.582 us; speedup vs baseline: 1.6901x; 1.6901x over previous
//
#include <hip/hip_runtime.h>
#include <math.h>

#define ND  256    // num_data (steps)
#define SEQ 2048
#define NI  256
#define NH  1024
#define NO  256

#define RB   64                 // recur blocks (all co-resident: 1 block/CU)
#define RT   1024               // recur threads (16 waves)
#define HPB  16                 // hidden units per block (NH / RB)
#define NHP  (NH + 1)           // padded LDS row (break 16-way write conflicts)

#define XTB  32                 // t-tile for xproj
#define OTB  8                  // t-tile for outproj

// relaxed agent-scope atomics: compile to sc0|sc1 ops that bypass/write-through
// L1+L2 to the device coherence point (IF) — no buffer_wbl2/buffer_inv needed.
#define AL(p)    __hip_atomic_load((p), __ATOMIC_RELAXED, __HIP_MEMORY_SCOPE_AGENT)
#define AS(p,v)  __hip_atomic_store((p), (v), __ATOMIC_RELAXED, __HIP_MEMORY_SCOPE_AGENT)

// ---------------- input projections, t-tiled: X[t][h] = b[h] + x[t,2047,:]@W --
__global__ void xproj(const float* __restrict__ x,
                      const float* __restrict__ Win1, const float* __restrict__ b1,
                      const float* __restrict__ Win2, const float* __restrict__ b2,
                      float* __restrict__ X1, float* __restrict__ X2) {
    const int   layer = blockIdx.z;
    const int   t0    = blockIdx.y * XTB;
    const int   h     = blockIdx.x * 256 + threadIdx.x;
    const float* W = layer ? Win2 : Win1;
    const float* b = layer ? b2   : b1;
    float*       X = layer ? X2   : X1;

    __shared__ float lx[XTB][NI];          // 32 KB: last seq row for 32 t's
    for (int idx = threadIdx.x; idx < XTB * NI; idx += 256) {
        int r = idx >> 8, c = idx & (NI - 1);
        lx[r][c] = x[(size_t)(t0 + r) * SEQ * NI + (size_t)(SEQ - 1) * NI + c];
    }
    __syncthreads();

    float acc[XTB];
    float bias = b[h];
    #pragma unroll
    for (int r = 0; r < XTB; ++r) acc[r] = bias;

    for (int i = 0; i < NI; ++i) {
        float wv = W[i * NH + h];          // coalesced over h, L1/L2-cached
        #pragma unroll
        for (int r = 0; r < XTB; ++r) acc[r] += lx[r][i] * wv;
    }
    #pragma unroll
    for (int r = 0; r < XTB; ++r) X[(t0 + r) * NH + h] = acc[r];
}

// ---------------- sequential recurrence: 64 blocks, weights LDS-resident -----
__launch_bounds__(RT, 1)
__global__ void recur(const float* __restrict__ Wr1, const float* __restrict__ Wr2,
                      const float* __restrict__ X1,  const float* __restrict__ X2,
                      float* Z12, float* Z2, float* Z1hist, int* bar) {
    __shared__ float lW1[HPB][NHP];        // 64 KB (+pad)
    __shared__ float lW2[HPB][NHP];        // 64 KB (+pad)
    __shared__ float sz [NH];              // 4 KB  z12 staging
    __shared__ float sz2[NH];              // 4 KB  z2 staging

    const int tid = threadIdx.x;
    const int h0  = blockIdx.x * HPB;

    // one-time weight residency: consecutive tid -> consecutive h (64B chunks)
    for (int idx = tid; idx < HPB * NH; idx += RT) {
        int hw = idx & (HPB - 1);
        int k  = idx >> 4;                 // HPB == 16
        lW1[hw][k] = Wr1[(size_t)k * NH + h0 + hw];
        lW2[hw][k] = Wr2[(size_t)k * NH + h0 + hw];
    }
    __syncthreads();

    const int w = tid >> 6;                // wave 0..15 <-> hidden unit
    const int l = tid & 63;
    const int h = h0 + w;

    float z2h = 0.0f;                      // lane-0-owned z2[h] register state
    int   cur = 0;

    int* cnt = bar + 32;                   // own 128B line
    int* gen = bar + 64;                   // own 128B line

    for (int t = 0; t < ND; ++t) {
        const bool even = (t & 1) == 0;

        // stage z vectors: one uncached load per thread
        sz[tid] = AL(Z12 + cur * NH + tid);
        if (even) sz2[tid] = AL(Z2 + ((t >> 1) & 1) * NH + tid);
        __syncthreads();

        float xv1 = X1[t * NH + h];        // cached broadcast load
        float r1 = 0.0f, r2 = 0.0f, xv2 = 0.0f;
        #pragma unroll
        for (int j = 0; j < 16; ++j) {
            int k = l + 64 * j;            // conflict-free LDS
            r1 += sz[k] * lW1[w][k];
        }
        if (even) {
            xv2 = X2[t * NH + h];
            #pragma unroll
            for (int j = 0; j < 16; ++j) {
                int k = l + 64 * j;
                r2 += sz2[k] * lW2[w][k];
            }
        }
        #pragma unroll
        for (int off = 32; off; off >>= 1) {
            r1 += __shfl_xor(r1, off, 64);
            r2 += __shfl_xor(r2, off, 64);
        }

        if (l == 0) {
            float z1n = tanhf(xv1 + r1);
            if (even) z2h = tanhf(xv2 + r2);
            Z1hist[t * NH + h] = z1n;                      // cached (intra-kernel private)
            AS(Z12 + (cur ^ 1) * NH + h, z1n + z2h);       // uncached publish
            if (even) AS(Z2 + (((t >> 1) & 1) ^ 1) * NH + h, z2h);
        }
        cur ^= 1;

        if (t == ND - 1) break;            // nothing to sync after last step

        __builtin_amdgcn_s_waitcnt(0);     // this wave's write-through stores at IF
        __syncthreads();                   // => all waves' stores globally visible
        if (tid == 0) {
            int g = AL(gen);
            int a = __hip_atomic_fetch_add(cnt, 1, __ATOMIC_RELAXED,
                                           __HIP_MEMORY_SCOPE_AGENT);
            if (a == RB - 1) {
                AS(cnt, 0);
                AS(gen, g + 1);
            } else {
                while (AL(gen) == g) { }
            }
        }
        __syncthreads();
    }
}

// ---------------- output projection, t-tiled: out[t] = tanh(z1[t]@Wout + b) --
__global__ void outproj(const float* __restrict__ Z1hist,
                        const float* __restrict__ Wout,
                        const float* __restrict__ bout,
                        float* __restrict__ out) {
    const int t0 = blockIdx.x * OTB;
    const int o  = threadIdx.x;

    __shared__ float lz[OTB][NH];          // 32 KB
    for (int idx = threadIdx.x; idx < OTB * NH; idx += 256) {
        int r = idx >> 10, c = idx & (NH - 1);
        lz[r][c] = Z1hist[(t0 + r) * NH + c];
    }
    __syncthreads();

    float acc[OTB];
    float bias = bout[o];
    #pragma unroll
    for (int r = 0; r < OTB; ++r) acc[r] = bias;

    for (int hh = 0; hh < NH; ++hh) {
        float wv = Wout[hh * NO + o];      // coalesced over o
        #pragma unroll
        for (int r = 0; r < OTB; ++r) acc[r] += lz[r][hh] * wv;
    }
    #pragma unroll
    for (int r = 0; r < OTB; ++r) out[(t0 + r) * NO + o] = tanhf(acc[r]);
}

extern "C" void kernel_launch(void* const* d_in, const int* in_sizes, int n_in,
                              void* d_out, int out_size, void* d_ws, size_t ws_size,
                              hipStream_t stream) {
    const float* x     = (const float*)d_in[0];
    const float* Win1  = (const float*)d_in[1];
    const float* b1    = (const float*)d_in[2];
    const float* Wr1   = (const float*)d_in[3];
    const float* Win2  = (const float*)d_in[4];
    const float* b2    = (const float*)d_in[5];
    const float* Wr2   = (const float*)d_in[6];
    const float* Wout  = (const float*)d_in[7];
    const float* bout  = (const float*)d_in[8];
    float* out = (float*)d_out;

    // workspace layout (floats)
    float* ws   = (float*)d_ws;
    float* Z12  = ws;                       // 2*NH   ping-pong z1+z2
    float* Z2   = Z12 + 2 * NH;             // 2*NH   ping-pong z2 (even steps)
    int*   bar  = (int*)(Z2 + 2 * NH);      // 128 ints (cnt @+32, gen @+64)
    float* Z1h  = (float*)(bar + 128);      // ND*NH
    float* X1   = Z1h + ND * NH;            // ND*NH
    float* X2   = X1 + ND * NH;             // ND*NH

    // zero initial state + barrier vars (ws is re-poisoned before every call)
    hipMemsetAsync(Z12, 0, (4 * NH) * sizeof(float) + 128 * sizeof(int), stream);

    dim3 xg(NH / 256, ND / XTB, 2);
    xproj<<<xg, 256, 0, stream>>>(x, Win1, b1, Win2, b2, X1, X2);

    recur<<<RB, RT, 0, stream>>>(Wr1, Wr2, X1, X2, Z12, Z2, Z1h, bar);

    outproj<<<ND / OTB, NO, 0, stream>>>(Z1h, Wout, bout, out);
}